// Round 11
// baseline (484.794 us; speedup 1.0000x reference)
//
#include <hip/hip_runtime.h>

#define NND 50000
#define NED 1600000
#define EPSBN 1e-5f
#define NB 196          // buckets of 256 nodes (bin = dst >> 8); also scatter block count
#define EPB 8192        // edges per scatter/hist block: 196*8192 >= NED
#define SCELEM (NB * NB)        // 38416
#define SCPAD (38 * 1024)       // 38912: scan_p1 coverage

typedef __attribute__((ext_vector_type(8))) short short8;
typedef __attribute__((ext_vector_type(4))) float f32x4;

__device__ __forceinline__ float bf_lo(unsigned u) {
    union { unsigned u; float f; } c; c.u = u << 16; return c.f;
}
__device__ __forceinline__ float bf_hi(unsigned u) {
    union { unsigned u; float f; } c; c.u = u & 0xffff0000u; return c.f;
}
__device__ __forceinline__ unsigned short f2b(float f) {
    union { float f; unsigned u; } c; c.f = f;
    unsigned r = (c.u + 0x7fffu + ((c.u >> 16) & 1u)) >> 16;
    return (unsigned short)r;
}

// ---------------- fp32 -> bf16 cast (8 elems/thread) ----------------
__global__ __launch_bounds__(256) void cast_bf16_kernel(const float* __restrict__ x,
                                                        unsigned short* __restrict__ xb) {
    int i = blockIdx.x * 256 + threadIdx.x;
    if (i >= NND * 16) return;
    const float4* p = (const float4*)x + (size_t)i * 2;
    float4 a = p[0], b = p[1];
    uint4 o;
    o.x = f2b(a.x) | ((unsigned)f2b(a.y) << 16);
    o.y = f2b(a.z) | ((unsigned)f2b(a.w) << 16);
    o.z = f2b(b.x) | ((unsigned)f2b(b.y) << 16);
    o.w = f2b(b.z) | ((unsigned)f2b(b.w) << 16);
    ((uint4*)xb)[i] = o;
}

// ---------------- phase A: per-block bucket histogram -> cntT[bin][blk] (transposed) ----------------
__global__ __launch_bounds__(256) void eb_hist_kernel(const int* __restrict__ dst,
                                                      int* __restrict__ cntT) {
    __shared__ int hs[256];
    int t = threadIdx.x;
    hs[t] = 0;
    if (blockIdx.x == 0) {       // zero the scan pad tail [SCELEM, SCPAD)
        for (int i = t; i < SCPAD - SCELEM; i += 256) cntT[SCELEM + i] = 0;
    }
    __syncthreads();
    int base = blockIdx.x * EPB;
    for (int i = t; i < EPB; i += 256) {
        int e = base + i;
        if (e < NED) atomicAdd(&hs[dst[e] >> 8], 1);
    }
    __syncthreads();
    if (t < NB) cntT[t * NB + blockIdx.x] = hs[t];
}

// ---------------- phase B: multi-block exclusive scan of cntT (contiguous) ----------------
__global__ __launch_bounds__(1024) void scan_p1_kernel(int* __restrict__ cnt,
                                                       int* __restrict__ psum) {
    __shared__ int s[1024];
    int t = threadIdx.x;
    int idx = blockIdx.x * 1024 + t;
    int v = cnt[idx];
    s[t] = v;
    __syncthreads();
    for (int o = 1; o < 1024; o <<= 1) {
        int a = (t >= o) ? s[t - o] : 0;
        __syncthreads();
        s[t] += a;
        __syncthreads();
    }
    cnt[idx] = s[t] - v;                    // exclusive within block
    if (t == 1023) psum[blockIdx.x] = s[t];
}

__global__ __launch_bounds__(64) void scan_p2_kernel(int* __restrict__ psum,
                                                     int* __restrict__ binOff,
                                                     int* __restrict__ rowptr) {
    __shared__ int s[64];
    int t = threadIdx.x;
    int v = (t < 38) ? psum[t] : 0;
    s[t] = v;
    __syncthreads();
    for (int o = 1; o < 64; o <<= 1) {
        int a = (t >= o) ? s[t - o] : 0;
        __syncthreads();
        s[t] += a;
        __syncthreads();
    }
    if (t < 38) psum[t] = s[t] - v;
    if (t == 0) { binOff[NB] = NED; rowptr[NND] = NED; }
}

__global__ __launch_bounds__(1024) void scan_p3_kernel(int* __restrict__ cnt,
                                                       const int* __restrict__ psum,
                                                       int* __restrict__ binOff) {
    int idx = blockIdx.x * 1024 + threadIdx.x;
    int val = cnt[idx] + psum[blockIdx.x];
    cnt[idx] = val;
    int bin = idx / NB;
    if (bin < NB && idx - bin * NB == 0) binOff[bin] = val;
}

// ---------------- phase C: scatter pairs into block-exclusive contiguous runs ----------------
__global__ __launch_bounds__(256) void eb_scatter_kernel(const int* __restrict__ src,
                                                         const int* __restrict__ dst,
                                                         const int* __restrict__ offT,
                                                         unsigned* __restrict__ pairs) {
    __shared__ int cur[256];
    int t = threadIdx.x;
    if (t < NB) cur[t] = offT[t * NB + blockIdx.x];
    __syncthreads();
    int base = blockIdx.x * EPB;
    for (int i = t; i < EPB; i += 256) {
        int e = base + i;
        if (e < NED) {
            int d = dst[e];
            int pos = atomicAdd(&cur[d >> 8], 1);
            pairs[pos] = ((unsigned)src[e] << 8) | (unsigned)(d & 255);
        }
    }
}

// ---------------- phase D: per-bucket LDS hist + scan -> rowptr/dinv, L2-local csr scatter ----------------
__global__ __launch_bounds__(256) void bucket_finalize_kernel(const unsigned* __restrict__ pairs,
                                                              const int* __restrict__ binOff,
                                                              int* __restrict__ rowptr,
                                                              float* __restrict__ dinv,
                                                              int* __restrict__ csr) {
    __shared__ int hist[256], s[256], cur[256];
    int b = blockIdx.x, t = threadIdx.x;
    int beg = binOff[b], end = binOff[b + 1];
    hist[t] = 0;
    __syncthreads();
    for (int e = beg + t; e < end; e += 256)
        atomicAdd(&hist[pairs[e] & 255u], 1);
    __syncthreads();
    int v = hist[t];
    s[t] = v;
    __syncthreads();
#pragma unroll
    for (int o = 1; o < 256; o <<= 1) {
        int a = (t >= o) ? s[t - o] : 0;
        __syncthreads();
        s[t] += a;
        __syncthreads();
    }
    int base = beg + s[t] - v;      // global csr start of node b*256+t
    int node = b * 256 + t;
    if (node < NND) {
        rowptr[node] = base;
        dinv[node] = 1.0f / (float)(v > 1 ? v : 1);
    }
    cur[t] = base;
    __syncthreads();
    for (int e = beg + t; e < end; e += 256) {
        unsigned p = pairs[e];
        int pos = atomicAdd(&cur[p & 255u], 1);
        csr[pos] = (int)(p >> 8);    // lands in this bucket's ~32KB window
    }
}

// ---------------- pack all 3 layers' W into MFMA-fragment-major bf16 + zero stats ----------------
__global__ __launch_bounds__(256) void pack_all_kernel(const float* __restrict__ Wl0,
                                                       const float* __restrict__ Wr0,
                                                       const float* __restrict__ Wl1,
                                                       const float* __restrict__ Wr1,
                                                       const float* __restrict__ Wl2,
                                                       const float* __restrict__ Wr2,
                                                       unsigned short* __restrict__ wp0,
                                                       unsigned short* __restrict__ wp1,
                                                       unsigned short* __restrict__ wp2,
                                                       float* __restrict__ stats) {
    int blk = blockIdx.x;
    if (blk == 0) { stats[threadIdx.x] = 0.f; stats[256 + threadIdx.x] = 0.f; }
    const float *Wl, *Wr; unsigned short* wp; bool l2f; int t;
    if (blk < 16)      { Wl = Wl0; Wr = Wr0; wp = wp0; l2f = false; t = blk * 256 + threadIdx.x; }
    else if (blk < 32) { Wl = Wl1; Wr = Wr1; wp = wp1; l2f = false; t = (blk - 16) * 256 + threadIdx.x; }
    else               { Wl = Wl2; Wr = Wr2; wp = wp2; l2f = true;  t = (blk - 32) * 256 + threadIdx.x; }
    int rem = t & 511;
    int ks = t >> 9;
    int cf = rem >> 6, l = rem & 63;
    int c = cf * 16 + (l & 15);
    int kb = ks * 32 + ((l >> 4) * 8);
    unsigned short v[8];
#pragma unroll
    for (int j = 0; j < 8; ++j) {
        int k = kb + j;
        float w;
        if (l2f) w = (c < 64) ? Wl[c * 128 + k] : Wr[(c - 64) * 128 + k];
        else     w = (k < 128) ? Wl[c * 128 + k] : Wr[c * 128 + (k - 128)];
        v[j] = f2b(w);
    }
    uint4 o;
    o.x = v[0] | ((unsigned)v[1] << 16);
    o.y = v[2] | ((unsigned)v[3] << 16);
    o.z = v[4] | ((unsigned)v[5] << 16);
    o.w = v[6] | ((unsigned)v[7] << 16);
    ((uint4*)wp)[t] = o;
}

// ---------------- FUSED layer 0/1: gather(64 rows -> LDS) + dual-GEMM + BN stats ----------------
// Each wave gathers its own 16 rows into As (row stride 136 elems = 4-bank shift ->
// <=2-way LDS conflicts), then the MFMA loop reads the agg half from As and the x half
// from global. out must NOT alias xb (other blocks still gather xb rows).
union FSm {
    unsigned short As[64][136];
    struct {
        float o_s[64][132];
        float sum_s[4][128];
        float sq_s[4][128];
    } e;
};

__global__ __launch_bounds__(256) void fused_l01_kernel(const unsigned short* __restrict__ xb,
                                                        const int* __restrict__ rowptr,
                                                        const int* __restrict__ csr,
                                                        const float* __restrict__ dinv,
                                                        const unsigned short* __restrict__ wpack,
                                                        unsigned short* __restrict__ out,
                                                        float* __restrict__ stats) {
    __shared__ FSm sm;
    const int t = threadIdx.x, wave = t >> 6, lane = t & 63;
    const int row0 = blockIdx.x * 64;
    const int q = lane >> 4, c8 = lane & 15;
    const uint4* xv = (const uint4*)xb;

    // ---- phase 1: gather this wave's 16 rows into As ----
    for (int n = 0; n < 16; ++n) {
        int node = row0 + wave * 16 + n;
        if (node >= NND) break;
        int beg = rowptr[node], end = rowptr[node + 1];
        float acc[8];
#pragma unroll
        for (int i = 0; i < 8; ++i) acc[i] = 0.f;
        for (int j = beg + q; j < end; j += 4) {
            int s = csr[j];
            uint4 v = xv[(size_t)s * 16 + c8];
            acc[0] += bf_lo(v.x); acc[1] += bf_hi(v.x);
            acc[2] += bf_lo(v.y); acc[3] += bf_hi(v.y);
            acc[4] += bf_lo(v.z); acc[5] += bf_hi(v.z);
            acc[6] += bf_lo(v.w); acc[7] += bf_hi(v.w);
        }
#pragma unroll
        for (int i = 0; i < 8; ++i) {
            acc[i] += __shfl_xor(acc[i], 16);
            acc[i] += __shfl_xor(acc[i], 32);
        }
        if (q == 0) {
            float dv = dinv[node];
            uint4 o;
            o.x = f2b(acc[0] * dv) | ((unsigned)f2b(acc[1] * dv) << 16);
            o.y = f2b(acc[2] * dv) | ((unsigned)f2b(acc[3] * dv) << 16);
            o.z = f2b(acc[4] * dv) | ((unsigned)f2b(acc[5] * dv) << 16);
            o.w = f2b(acc[6] * dv) | ((unsigned)f2b(acc[7] * dv) << 16);
            *(uint4*)&sm.As[wave * 16 + n][c8 * 8] = o;
        }
    }
    __syncthreads();

    // ---- phase 2: MFMA (agg half from As, x half from global) ----
    const int arow = row0 + wave * 16 + (lane & 15);
    const bool avalid = arow < NND;
    const int ko = (lane >> 4) * 8;

    f32x4 acc[8];
#pragma unroll
    for (int cf = 0; cf < 8; ++cf) acc[cf] = (f32x4){0.f, 0.f, 0.f, 0.f};

    const short8* wp = (const short8*)wpack;
#pragma unroll
    for (int ks = 0; ks < 8; ++ks) {
        short8 a = {0, 0, 0, 0, 0, 0, 0, 0};
        if (avalid) {
            if (ks < 4)
                a = *(const short8*)&sm.As[wave * 16 + (lane & 15)][ks * 32 + ko];
            else
                a = *(const short8*)(xb + (size_t)arow * 128 + (ks - 4) * 32 + ko);
        }
#pragma unroll
        for (int cf = 0; cf < 8; ++cf) {
            short8 b = wp[(ks * 8 + cf) * 64 + lane];
            acc[cf] = __builtin_amdgcn_mfma_f32_16x16x32_bf16(a, b, acc[cf], 0, 0, 0);
        }
    }
    __syncthreads();    // all As reads done before o_s overwrites the union

    // ---- epilogue: stage C + BN partial stats ----
#pragma unroll
    for (int cf = 0; cf < 8; ++cf)
#pragma unroll
        for (int r = 0; r < 4; ++r)
            sm.e.o_s[wave * 16 + (lane >> 4) * 4 + r][cf * 16 + (lane & 15)] = acc[cf][r];

#pragma unroll
    for (int cf = 0; cf < 8; ++cf) {
        float s = acc[cf][0] + acc[cf][1] + acc[cf][2] + acc[cf][3];
        float qq = acc[cf][0] * acc[cf][0] + acc[cf][1] * acc[cf][1]
                 + acc[cf][2] * acc[cf][2] + acc[cf][3] * acc[cf][3];
        s += __shfl_xor(s, 16); s += __shfl_xor(s, 32);
        qq += __shfl_xor(qq, 16); qq += __shfl_xor(qq, 32);
        if (lane < 16) {
            sm.e.sum_s[wave][cf * 16 + lane] = s;
            sm.e.sq_s[wave][cf * 16 + lane] = qq;
        }
    }
    __syncthreads();

    const int r = t >> 2, qc = t & 3;
    const int grow = row0 + r;
    if (grow < NND) {
        const int c0 = qc * 32;
#pragma unroll
        for (int g = 0; g < 4; ++g) {   // 8 bf16 per uint4
            float v0 = sm.e.o_s[r][c0 + g * 8 + 0], v1 = sm.e.o_s[r][c0 + g * 8 + 1];
            float v2 = sm.e.o_s[r][c0 + g * 8 + 2], v3 = sm.e.o_s[r][c0 + g * 8 + 3];
            float v4 = sm.e.o_s[r][c0 + g * 8 + 4], v5 = sm.e.o_s[r][c0 + g * 8 + 5];
            float v6 = sm.e.o_s[r][c0 + g * 8 + 6], v7 = sm.e.o_s[r][c0 + g * 8 + 7];
            uint4 o;
            o.x = f2b(v0) | ((unsigned)f2b(v1) << 16);
            o.y = f2b(v2) | ((unsigned)f2b(v3) << 16);
            o.z = f2b(v4) | ((unsigned)f2b(v5) << 16);
            o.w = f2b(v6) | ((unsigned)f2b(v7) << 16);
            ((uint4*)(out + (size_t)grow * 128 + c0))[g] = o;
        }
    }

    if (t < 128) {
        float s = sm.e.sum_s[0][t] + sm.e.sum_s[1][t] + sm.e.sum_s[2][t] + sm.e.sum_s[3][t];
        float qq = sm.e.sq_s[0][t] + sm.e.sq_s[1][t] + sm.e.sq_s[2][t] + sm.e.sq_s[3][t];
        unsafeAtomicAdd(&stats[t], s);
        unsafeAtomicAdd(&stats[128 + t], qq);
    }
}

// ---------------- layer-2 GEMM (round-4/6 proven form, MODE 2 only) ----------------
// A=xinb K=128 (KS=4), cols 0..63 -> tbuf bf16, cols 64..127 -> fp32 out + bias.
__global__ __launch_bounds__(256) void gemm_l2_kernel(const unsigned short* __restrict__ xinb,
                                                      const unsigned short* __restrict__ wpack,
                                                      const float* __restrict__ bias,
                                                      float* __restrict__ outf,
                                                      unsigned short* __restrict__ tbuf) {
    __shared__ float o_s[64][132];
    const int t = threadIdx.x, wave = t >> 6, lane = t & 63;
    const int row0 = blockIdx.x * 64;
    const int arow = row0 + wave * 16 + (lane & 15);
    const bool avalid = arow < NND;
    const int ko = (lane >> 4) * 8;

    f32x4 acc[8];
#pragma unroll
    for (int cf = 0; cf < 8; ++cf) acc[cf] = (f32x4){0.f, 0.f, 0.f, 0.f};

    const short8* wp = (const short8*)wpack;
#pragma unroll
    for (int ks = 0; ks < 4; ++ks) {
        short8 a = {0, 0, 0, 0, 0, 0, 0, 0};
        if (avalid) a = *(const short8*)(xinb + (size_t)arow * 128 + ks * 32 + ko);
#pragma unroll
        for (int cf = 0; cf < 8; ++cf) {
            short8 b = wp[(ks * 8 + cf) * 64 + lane];
            acc[cf] = __builtin_amdgcn_mfma_f32_16x16x32_bf16(a, b, acc[cf], 0, 0, 0);
        }
    }

#pragma unroll
    for (int cf = 0; cf < 8; ++cf)
#pragma unroll
        for (int r = 0; r < 4; ++r)
            o_s[wave * 16 + (lane >> 4) * 4 + r][cf * 16 + (lane & 15)] = acc[cf][r];
    __syncthreads();

    const int r = t >> 2, q = t & 3;
    const int grow = row0 + r;
    if (grow < NND) {
        if (q < 2) {
            const int c0 = q * 32;      // cols 0..63 -> tbuf bf16
#pragma unroll
            for (int g = 0; g < 4; ++g) {
                float v0 = o_s[r][c0 + g * 8 + 0], v1 = o_s[r][c0 + g * 8 + 1];
                float v2 = o_s[r][c0 + g * 8 + 2], v3 = o_s[r][c0 + g * 8 + 3];
                float v4 = o_s[r][c0 + g * 8 + 4], v5 = o_s[r][c0 + g * 8 + 5];
                float v6 = o_s[r][c0 + g * 8 + 6], v7 = o_s[r][c0 + g * 8 + 7];
                uint4 o;
                o.x = f2b(v0) | ((unsigned)f2b(v1) << 16);
                o.y = f2b(v2) | ((unsigned)f2b(v3) << 16);
                o.z = f2b(v4) | ((unsigned)f2b(v5) << 16);
                o.w = f2b(v6) | ((unsigned)f2b(v7) << 16);
                ((uint4*)(tbuf + (size_t)grow * 64 + c0))[g] = o;
            }
        } else {
            const int c0 = (q - 2) * 32;  // cols 64..127 -> fp32 out + bias
#pragma unroll
            for (int g = 0; g < 8; ++g) {
                float4 o;
                o.x = o_s[r][64 + c0 + g * 4 + 0] + bias[c0 + g * 4 + 0];
                o.y = o_s[r][64 + c0 + g * 4 + 1] + bias[c0 + g * 4 + 1];
                o.z = o_s[r][64 + c0 + g * 4 + 2] + bias[c0 + g * 4 + 2];
                o.w = o_s[r][64 + c0 + g * 4 + 3] + bias[c0 + g * 4 + 3];
                ((float4*)(outf + (size_t)grow * 64 + c0))[g] = o;
            }
        }
    }
}

// ---------------- gather-mean 64ch of t, accumulate into fp32 out ----------------
__global__ __launch_bounds__(256) void gather64_kernel(const unsigned short* __restrict__ tb,
                                                       const int* __restrict__ rowptr,
                                                       const int* __restrict__ csr,
                                                       const float* __restrict__ dinv,
                                                       float* __restrict__ out) {
    int w = threadIdx.x >> 6;
    int node = blockIdx.x * 4 + w;
    if (node >= NND) return;
    int lane = threadIdx.x & 63;
    int g = lane >> 3;        // neighbor slot 0..7
    int c8 = lane & 7;        // uint4 chunk (8 channels of 64)
    int beg = rowptr[node], end = rowptr[node + 1];
    const uint4* tv = (const uint4*)tb;

    float acc[8];
#pragma unroll
    for (int i = 0; i < 8; ++i) acc[i] = 0.f;

    for (int j = beg + g; j < end; j += 8) {
        int s = csr[j];
        uint4 v = tv[(size_t)s * 8 + c8];
        acc[0] += bf_lo(v.x); acc[1] += bf_hi(v.x);
        acc[2] += bf_lo(v.y); acc[3] += bf_hi(v.y);
        acc[4] += bf_lo(v.z); acc[5] += bf_hi(v.z);
        acc[6] += bf_lo(v.w); acc[7] += bf_hi(v.w);
    }
#pragma unroll
    for (int i = 0; i < 8; ++i) {
        acc[i] += __shfl_xor(acc[i], 8);
        acc[i] += __shfl_xor(acc[i], 16);
        acc[i] += __shfl_xor(acc[i], 32);
    }
    if (g == 0) {
        float dv = dinv[node];
        float* po = out + (size_t)node * 64 + c8 * 8;
        float4 a = *(float4*)po, b = *(float4*)(po + 4);
        a.x += acc[0] * dv; a.y += acc[1] * dv; a.z += acc[2] * dv; a.w += acc[3] * dv;
        b.x += acc[4] * dv; b.y += acc[5] * dv; b.z += acc[6] * dv; b.w += acc[7] * dv;
        *(float4*)po = a; *(float4*)(po + 4) = b;
    }
}

// ---------------- BN finalize (per-block, from stats) + ReLU in place ----------------
__global__ __launch_bounds__(256) void bn_relu_kernel(unsigned short* __restrict__ h,
                                                      const float* __restrict__ stats,
                                                      const float* __restrict__ gamma,
                                                      const float* __restrict__ beta) {
    __shared__ float ab_s[256];
    int t = threadIdx.x;
    if (t < 128) {
        float mu = stats[t] * (1.0f / NND);
        float var = stats[128 + t] * (1.0f / NND) - mu * mu;
        float rs = rsqrtf(var + EPSBN);
        float a = gamma[t] * rs;
        ab_s[t] = a;
        ab_s[128 + t] = beta[t] - mu * a;
    }
    __syncthreads();
    int i = blockIdx.x * 256 + t;
    if (i >= NND * 16) return;
    uint4 v = ((uint4*)h)[i];
    int c0 = (i & 15) * 8;
    float o[8] = {bf_lo(v.x), bf_hi(v.x), bf_lo(v.y), bf_hi(v.y),
                  bf_lo(v.z), bf_hi(v.z), bf_lo(v.w), bf_hi(v.w)};
#pragma unroll
    for (int j = 0; j < 8; ++j)
        o[j] = fmaxf(o[j] * ab_s[c0 + j] + ab_s[128 + c0 + j], 0.f);
    uint4 w;
    w.x = f2b(o[0]) | ((unsigned)f2b(o[1]) << 16);
    w.y = f2b(o[2]) | ((unsigned)f2b(o[3]) << 16);
    w.z = f2b(o[4]) | ((unsigned)f2b(o[5]) << 16);
    w.w = f2b(o[6]) | ((unsigned)f2b(o[7]) << 16);
    ((uint4*)h)[i] = w;
}

extern "C" void kernel_launch(void* const* d_in, const int* in_sizes, int n_in,
                              void* d_out, int out_size, void* d_ws, size_t ws_size,
                              hipStream_t stream) {
    const float* x   = (const float*)d_in[0];
    const int*   ei  = (const int*)d_in[1];
    const int* src = ei;
    const int* dst = ei + NED;
    const float* Wl0 = (const float*)d_in[2];
    const float* Wr0 = (const float*)d_in[3];
    const float* g0  = (const float*)d_in[5];
    const float* be0 = (const float*)d_in[6];
    const float* Wl1 = (const float*)d_in[7];
    const float* Wr1 = (const float*)d_in[8];
    const float* g1  = (const float*)d_in[10];
    const float* be1 = (const float*)d_in[11];
    const float* Wl2 = (const float*)d_in[12];
    const float* Wr2 = (const float*)d_in[13];
    const float* b2  = (const float*)d_in[14];
    float* out = (float*)d_out;
    // b0/b1 unused: bias cancels under training-mode BatchNorm.

    // workspace (~45.8 MB): h2 (=pairs) | xb (reused as t) | h (bf16 NF each) |
    //   csr int | dinv | rowptr | binOff | cntT[SCPAD] | psum | wpack x3 | stats x2
    // pairs aliases h2: consumed by bucket_finalize before fused layer-1 writes h2.
    const size_t NF = (size_t)NND * 128;
    unsigned short* h2   = (unsigned short*)d_ws;
    unsigned short* xb   = h2 + NF;
    unsigned short* h    = xb + NF;
    int*   csr    = (int*)(h + NF);                // NED ints = 6.4 MB
    float* dinv   = (float*)(csr + NED);
    int*   rowptr = (int*)(dinv + NND);            // NND+1 used, pad to NND+8
    int*   binOff = rowptr + NND + 8;              // NB+1 -> pad 256
    int*   cntT   = binOff + 256;                  // SCPAD = 38912
    int*   psum   = cntT + SCPAD;                  // 38 -> pad 64
    unsigned short* wp0 = (unsigned short*)(psum + 64);
    unsigned short* wp1 = wp0 + 32768;
    unsigned short* wp2 = wp1 + 32768;
    float* stats  = (float*)(wp2 + 32768);         // [0..255]=L0, [256..511]=L1
    unsigned* pairs = (unsigned*)h2;

    const int GB = (NND + 3) / 4;       // gather64 blocks (4 nodes each)
    const int GM = (NND + 63) / 64;     // fused / gemm blocks

    // ---- bf16 cast + blocked counting-sort CSR build ----
    cast_bf16_kernel<<<(NND * 16 + 255) / 256, 256, 0, stream>>>(x, xb);
    eb_hist_kernel<<<NB, 256, 0, stream>>>(dst, cntT);
    scan_p1_kernel<<<38, 1024, 0, stream>>>(cntT, psum);
    scan_p2_kernel<<<1, 64, 0, stream>>>(psum, binOff, rowptr);
    scan_p3_kernel<<<38, 1024, 0, stream>>>(cntT, psum, binOff);
    eb_scatter_kernel<<<NB, 256, 0, stream>>>(src, dst, cntT, pairs);
    bucket_finalize_kernel<<<NB, 256, 0, stream>>>(pairs, binOff, rowptr, dinv, csr);
    pack_all_kernel<<<40, 256, 0, stream>>>(Wl0, Wr0, Wl1, Wr1, Wl2, Wr2, wp0, wp1, wp2, stats);

    // ---- layer 0: xb -> h (fused gather+GEMM) ----
    fused_l01_kernel<<<GM, 256, 0, stream>>>(xb, rowptr, csr, dinv, wp0, h, stats);
    bn_relu_kernel<<<(NND * 16 + 255) / 256, 256, 0, stream>>>(h, stats, g0, be0);

    // ---- layer 1: h -> h2 (fused; out-of-place into the dead pairs region) ----
    fused_l01_kernel<<<GM, 256, 0, stream>>>(h, rowptr, csr, dinv, wp1, h2, stats + 256);
    bn_relu_kernel<<<(NND * 16 + 255) / 256, 256, 0, stream>>>(h2, stats + 256, g1, be1);

    // ---- layer 2 (transform-before-aggregate):
    //      t = h2@Wl2^T (bf16, into xb), out = h2@Wr2^T + b2 (fp32), then out += gather_mean(t)
    gemm_l2_kernel<<<GM, 256, 0, stream>>>(h2, wp2, b2, out, xb);
    gather64_kernel<<<GB, 256, 0, stream>>>(xb, rowptr, csr, dinv, out);
}

// Round 12
// 400.958 us; speedup vs baseline: 1.2091x; 1.2091x over previous
//
#include <hip/hip_runtime.h>

#define NND 50000
#define NED 1600000
#define EPSBN 1e-5f
#define NB 196          // buckets of 256 nodes (bin = dst >> 8); also scatter block count
#define EPB 8192        // edges per scatter/hist block: 196*8192 >= NED
#define SCELEM (NB * NB)        // 38416
#define SCPAD (38 * 1024)       // 38912: scan_p1 coverage

typedef __attribute__((ext_vector_type(8))) short short8;
typedef __attribute__((ext_vector_type(4))) float f32x4;

__device__ __forceinline__ float bf_lo(unsigned u) {
    union { unsigned u; float f; } c; c.u = u << 16; return c.f;
}
__device__ __forceinline__ float bf_hi(unsigned u) {
    union { unsigned u; float f; } c; c.u = u & 0xffff0000u; return c.f;
}
__device__ __forceinline__ unsigned short f2b(float f) {
    union { float f; unsigned u; } c; c.f = f;
    unsigned r = (c.u + 0x7fffu + ((c.u >> 16) & 1u)) >> 16;
    return (unsigned short)r;
}

// ---------------- fp32 -> bf16 cast (8 elems/thread) ----------------
__global__ __launch_bounds__(256) void cast_bf16_kernel(const float* __restrict__ x,
                                                        unsigned short* __restrict__ xb) {
    int i = blockIdx.x * 256 + threadIdx.x;
    if (i >= NND * 16) return;
    const float4* p = (const float4*)x + (size_t)i * 2;
    float4 a = p[0], b = p[1];
    uint4 o;
    o.x = f2b(a.x) | ((unsigned)f2b(a.y) << 16);
    o.y = f2b(a.z) | ((unsigned)f2b(a.w) << 16);
    o.z = f2b(b.x) | ((unsigned)f2b(b.y) << 16);
    o.w = f2b(b.z) | ((unsigned)f2b(b.w) << 16);
    ((uint4*)xb)[i] = o;
}

// ---------------- phase A: per-block bucket histogram -> cntT[bin][blk] (transposed) ----------------
__global__ __launch_bounds__(256) void eb_hist_kernel(const int* __restrict__ dst,
                                                      int* __restrict__ cntT) {
    __shared__ int hs[256];
    int t = threadIdx.x;
    hs[t] = 0;
    if (blockIdx.x == 0) {       // zero the scan pad tail [SCELEM, SCPAD)
        for (int i = t; i < SCPAD - SCELEM; i += 256) cntT[SCELEM + i] = 0;
    }
    __syncthreads();
    int base = blockIdx.x * EPB;
    for (int i = t; i < EPB; i += 256) {
        int e = base + i;
        if (e < NED) atomicAdd(&hs[dst[e] >> 8], 1);
    }
    __syncthreads();
    if (t < NB) cntT[t * NB + blockIdx.x] = hs[t];
}

// ---------------- phase B: multi-block exclusive scan of cntT (contiguous) ----------------
__global__ __launch_bounds__(1024) void scan_p1_kernel(int* __restrict__ cnt,
                                                       int* __restrict__ psum) {
    __shared__ int s[1024];
    int t = threadIdx.x;
    int idx = blockIdx.x * 1024 + t;
    int v = cnt[idx];
    s[t] = v;
    __syncthreads();
    for (int o = 1; o < 1024; o <<= 1) {
        int a = (t >= o) ? s[t - o] : 0;
        __syncthreads();
        s[t] += a;
        __syncthreads();
    }
    cnt[idx] = s[t] - v;                    // exclusive within block
    if (t == 1023) psum[blockIdx.x] = s[t];
}

__global__ __launch_bounds__(64) void scan_p2_kernel(int* __restrict__ psum,
                                                     int* __restrict__ binOff,
                                                     int* __restrict__ rowptr) {
    __shared__ int s[64];
    int t = threadIdx.x;
    int v = (t < 38) ? psum[t] : 0;
    s[t] = v;
    __syncthreads();
    for (int o = 1; o < 64; o <<= 1) {
        int a = (t >= o) ? s[t - o] : 0;
        __syncthreads();
        s[t] += a;
        __syncthreads();
    }
    if (t < 38) psum[t] = s[t] - v;
    if (t == 0) { binOff[NB] = NED; rowptr[NND] = NED; }
}

__global__ __launch_bounds__(1024) void scan_p3_kernel(int* __restrict__ cnt,
                                                       const int* __restrict__ psum,
                                                       int* __restrict__ binOff) {
    int idx = blockIdx.x * 1024 + threadIdx.x;
    int val = cnt[idx] + psum[blockIdx.x];
    cnt[idx] = val;
    int bin = idx / NB;
    if (bin < NB && idx - bin * NB == 0) binOff[bin] = val;
}

// ---------------- phase C: scatter pairs into block-exclusive contiguous runs ----------------
__global__ __launch_bounds__(256) void eb_scatter_kernel(const int* __restrict__ src,
                                                         const int* __restrict__ dst,
                                                         const int* __restrict__ offT,
                                                         unsigned* __restrict__ pairs) {
    __shared__ int cur[256];
    int t = threadIdx.x;
    if (t < NB) cur[t] = offT[t * NB + blockIdx.x];
    __syncthreads();
    int base = blockIdx.x * EPB;
    for (int i = t; i < EPB; i += 256) {
        int e = base + i;
        if (e < NED) {
            int d = dst[e];
            int pos = atomicAdd(&cur[d >> 8], 1);
            pairs[pos] = ((unsigned)src[e] << 8) | (unsigned)(d & 255);
        }
    }
}

// ---------------- phase D: per-bucket LDS hist + scan -> rowptr/dinv, L2-local csr scatter ----------------
__global__ __launch_bounds__(256) void bucket_finalize_kernel(const unsigned* __restrict__ pairs,
                                                              const int* __restrict__ binOff,
                                                              int* __restrict__ rowptr,
                                                              float* __restrict__ dinv,
                                                              int* __restrict__ csr) {
    __shared__ int hist[256], s[256], cur[256];
    int b = blockIdx.x, t = threadIdx.x;
    int beg = binOff[b], end = binOff[b + 1];
    hist[t] = 0;
    __syncthreads();
    for (int e = beg + t; e < end; e += 256)
        atomicAdd(&hist[pairs[e] & 255u], 1);
    __syncthreads();
    int v = hist[t];
    s[t] = v;
    __syncthreads();
#pragma unroll
    for (int o = 1; o < 256; o <<= 1) {
        int a = (t >= o) ? s[t - o] : 0;
        __syncthreads();
        s[t] += a;
        __syncthreads();
    }
    int base = beg + s[t] - v;      // global csr start of node b*256+t
    int node = b * 256 + t;
    if (node < NND) {
        rowptr[node] = base;
        dinv[node] = 1.0f / (float)(v > 1 ? v : 1);
    }
    cur[t] = base;
    __syncthreads();
    for (int e = beg + t; e < end; e += 256) {
        unsigned p = pairs[e];
        int pos = atomicAdd(&cur[p & 255u], 1);
        csr[pos] = (int)(p >> 8);    // lands in this bucket's ~32KB window
    }
}

// ---------------- gather-mean 128ch: 1 wave/node, 2x unrolled for MLP ----------------
__global__ __launch_bounds__(256) void gather128_kernel(const unsigned short* __restrict__ xb,
                                                        const int* __restrict__ rowptr,
                                                        const int* __restrict__ csr,
                                                        const float* __restrict__ dinv,
                                                        unsigned short* __restrict__ aggb) {
    int w = threadIdx.x >> 6;
    int node = blockIdx.x * 4 + w;
    if (node >= NND) return;
    int lane = threadIdx.x & 63;
    int q = lane >> 4;        // neighbor slot 0..3
    int c8 = lane & 15;       // uint4 chunk (8 channels)
    int beg = rowptr[node], end = rowptr[node + 1];
    const uint4* xv = (const uint4*)xb;

    float acc[8];
#pragma unroll
    for (int i = 0; i < 8; ++i) acc[i] = 0.f;

    int j = beg + q;
    // 2-deep: two independent index+row loads in flight per lane
    for (; j + 4 < end; j += 8) {
        int s0 = csr[j], s1 = csr[j + 4];
        uint4 v0 = xv[(size_t)s0 * 16 + c8];
        uint4 v1 = xv[(size_t)s1 * 16 + c8];
        acc[0] += bf_lo(v0.x); acc[1] += bf_hi(v0.x);
        acc[2] += bf_lo(v0.y); acc[3] += bf_hi(v0.y);
        acc[4] += bf_lo(v0.z); acc[5] += bf_hi(v0.z);
        acc[6] += bf_lo(v0.w); acc[7] += bf_hi(v0.w);
        acc[0] += bf_lo(v1.x); acc[1] += bf_hi(v1.x);
        acc[2] += bf_lo(v1.y); acc[3] += bf_hi(v1.y);
        acc[4] += bf_lo(v1.z); acc[5] += bf_hi(v1.z);
        acc[6] += bf_lo(v1.w); acc[7] += bf_hi(v1.w);
    }
    if (j < end) {
        int s = csr[j];
        uint4 v = xv[(size_t)s * 16 + c8];
        acc[0] += bf_lo(v.x); acc[1] += bf_hi(v.x);
        acc[2] += bf_lo(v.y); acc[3] += bf_hi(v.y);
        acc[4] += bf_lo(v.z); acc[5] += bf_hi(v.z);
        acc[6] += bf_lo(v.w); acc[7] += bf_hi(v.w);
    }
#pragma unroll
    for (int i = 0; i < 8; ++i) {
        acc[i] += __shfl_xor(acc[i], 16);
        acc[i] += __shfl_xor(acc[i], 32);
    }
    if (q == 0) {
        float dv = dinv[node];
        uint4 o;
        o.x = f2b(acc[0] * dv) | ((unsigned)f2b(acc[1] * dv) << 16);
        o.y = f2b(acc[2] * dv) | ((unsigned)f2b(acc[3] * dv) << 16);
        o.z = f2b(acc[4] * dv) | ((unsigned)f2b(acc[5] * dv) << 16);
        o.w = f2b(acc[6] * dv) | ((unsigned)f2b(acc[7] * dv) << 16);
        ((uint4*)aggb)[(size_t)node * 16 + c8] = o;
    }
}

// ---------------- gather-mean 64ch of t into fp32 out, 2x unrolled ----------------
__global__ __launch_bounds__(256) void gather64_kernel(const unsigned short* __restrict__ tb,
                                                       const int* __restrict__ rowptr,
                                                       const int* __restrict__ csr,
                                                       const float* __restrict__ dinv,
                                                       float* __restrict__ out) {
    int w = threadIdx.x >> 6;
    int node = blockIdx.x * 4 + w;
    if (node >= NND) return;
    int lane = threadIdx.x & 63;
    int g = lane >> 3;        // neighbor slot 0..7
    int c8 = lane & 7;        // uint4 chunk (8 channels of 64)
    int beg = rowptr[node], end = rowptr[node + 1];
    const uint4* tv = (const uint4*)tb;

    float acc[8];
#pragma unroll
    for (int i = 0; i < 8; ++i) acc[i] = 0.f;

    int j = beg + g;
    for (; j + 8 < end; j += 16) {
        int s0 = csr[j], s1 = csr[j + 8];
        uint4 v0 = tv[(size_t)s0 * 8 + c8];
        uint4 v1 = tv[(size_t)s1 * 8 + c8];
        acc[0] += bf_lo(v0.x); acc[1] += bf_hi(v0.x);
        acc[2] += bf_lo(v0.y); acc[3] += bf_hi(v0.y);
        acc[4] += bf_lo(v0.z); acc[5] += bf_hi(v0.z);
        acc[6] += bf_lo(v0.w); acc[7] += bf_hi(v0.w);
        acc[0] += bf_lo(v1.x); acc[1] += bf_hi(v1.x);
        acc[2] += bf_lo(v1.y); acc[3] += bf_hi(v1.y);
        acc[4] += bf_lo(v1.z); acc[5] += bf_hi(v1.z);
        acc[6] += bf_lo(v1.w); acc[7] += bf_hi(v1.w);
    }
    if (j < end) {
        int s = csr[j];
        uint4 v = tv[(size_t)s * 8 + c8];
        acc[0] += bf_lo(v.x); acc[1] += bf_hi(v.x);
        acc[2] += bf_lo(v.y); acc[3] += bf_hi(v.y);
        acc[4] += bf_lo(v.z); acc[5] += bf_hi(v.z);
        acc[6] += bf_lo(v.w); acc[7] += bf_hi(v.w);
    }
#pragma unroll
    for (int i = 0; i < 8; ++i) {
        acc[i] += __shfl_xor(acc[i], 8);
        acc[i] += __shfl_xor(acc[i], 16);
        acc[i] += __shfl_xor(acc[i], 32);
    }
    if (g == 0) {
        float dv = dinv[node];
        float* po = out + (size_t)node * 64 + c8 * 8;
        float4 a = *(float4*)po, b = *(float4*)(po + 4);
        a.x += acc[0] * dv; a.y += acc[1] * dv; a.z += acc[2] * dv; a.w += acc[3] * dv;
        b.x += acc[4] * dv; b.y += acc[5] * dv; b.z += acc[6] * dv; b.w += acc[7] * dv;
        *(float4*)po = a; *(float4*)(po + 4) = b;
    }
}

// ---------------- pack all 3 layers' W into MFMA-fragment-major bf16 + zero stats ----------------
__global__ __launch_bounds__(256) void pack_all_kernel(const float* __restrict__ Wl0,
                                                       const float* __restrict__ Wr0,
                                                       const float* __restrict__ Wl1,
                                                       const float* __restrict__ Wr1,
                                                       const float* __restrict__ Wl2,
                                                       const float* __restrict__ Wr2,
                                                       unsigned short* __restrict__ wp0,
                                                       unsigned short* __restrict__ wp1,
                                                       unsigned short* __restrict__ wp2,
                                                       float* __restrict__ stats) {
    int blk = blockIdx.x;
    if (blk == 0) { stats[threadIdx.x] = 0.f; stats[256 + threadIdx.x] = 0.f; }
    const float *Wl, *Wr; unsigned short* wp; bool l2f; int t;
    if (blk < 16)      { Wl = Wl0; Wr = Wr0; wp = wp0; l2f = false; t = blk * 256 + threadIdx.x; }
    else if (blk < 32) { Wl = Wl1; Wr = Wr1; wp = wp1; l2f = false; t = (blk - 16) * 256 + threadIdx.x; }
    else               { Wl = Wl2; Wr = Wr2; wp = wp2; l2f = true;  t = (blk - 32) * 256 + threadIdx.x; }
    int rem = t & 511;
    int ks = t >> 9;
    int cf = rem >> 6, l = rem & 63;
    int c = cf * 16 + (l & 15);
    int kb = ks * 32 + ((l >> 4) * 8);
    unsigned short v[8];
#pragma unroll
    for (int j = 0; j < 8; ++j) {
        int k = kb + j;
        float w;
        if (l2f) w = (c < 64) ? Wl[c * 128 + k] : Wr[(c - 64) * 128 + k];
        else     w = (k < 128) ? Wl[c * 128 + k] : Wr[c * 128 + (k - 128)];
        v[j] = f2b(w);
    }
    uint4 o;
    o.x = v[0] | ((unsigned)v[1] << 16);
    o.y = v[2] | ((unsigned)v[3] << 16);
    o.z = v[4] | ((unsigned)v[5] << 16);
    o.w = v[6] | ((unsigned)v[7] << 16);
    ((uint4*)wp)[t] = o;
}

// ---------------- MFMA GEMM, direct A-fragment loads (round-4/6 proven form) ----------------
// MODE 0: A=[aggb|xinb] K=256 (KS=8), out=bf16 128ch + BN stats (no bias: BN absorbs).
// MODE 2: A=xinb K=128 (KS=4), cols 0..63 -> tbuf bf16, cols 64..127 -> fp32 out + bias.
// out may alias xinb in MODE 0 (each thread reads only rows it later writes; all A reads
// complete before the post-MFMA __syncthreads and stores).
template<int KS, int MODE>
__global__ __launch_bounds__(256) void gemm_mfma_kernel(const unsigned short* __restrict__ aggb,
                                                        const unsigned short* xinb,
                                                        const unsigned short* __restrict__ wpack,
                                                        const float* __restrict__ bias,
                                                        void* outv,
                                                        unsigned short* __restrict__ tbuf,
                                                        float* __restrict__ stats) {
    constexpr int NCF = 8, NCOL = 128;
    constexpr bool ST = (MODE == 0);
    __shared__ float o_s[64][NCOL + 4];
    __shared__ float sum_s[ST ? 4 : 1][ST ? 128 : 1];
    __shared__ float sq_s[ST ? 4 : 1][ST ? 128 : 1];

    const int t = threadIdx.x, wave = t >> 6, lane = t & 63;
    const int row0 = blockIdx.x * 64;
    const int arow = row0 + wave * 16 + (lane & 15);
    const bool avalid = arow < NND;
    const int ko = (lane >> 4) * 8;

    f32x4 acc[NCF];
#pragma unroll
    for (int cf = 0; cf < NCF; ++cf) acc[cf] = (f32x4){0.f, 0.f, 0.f, 0.f};

    const short8* wp = (const short8*)wpack;
#pragma unroll
    for (int ks = 0; ks < KS; ++ks) {
        short8 a = {0, 0, 0, 0, 0, 0, 0, 0};
        if (avalid) {
            int k = ks * 32 + ko;
            const unsigned short* base;
            if (MODE == 0)
                base = (k < 128) ? (aggb + (size_t)arow * 128 + k)
                                 : (xinb + (size_t)arow * 128 + (k - 128));
            else
                base = xinb + (size_t)arow * 128 + k;
            a = *(const short8*)base;
        }
#pragma unroll
        for (int cf = 0; cf < NCF; ++cf) {
            short8 b = wp[(ks * NCF + cf) * 64 + lane];
            acc[cf] = __builtin_amdgcn_mfma_f32_16x16x32_bf16(a, b, acc[cf], 0, 0, 0);
        }
    }

    // stage C into LDS for coalesced pass-2 stores
#pragma unroll
    for (int cf = 0; cf < NCF; ++cf)
#pragma unroll
        for (int r = 0; r < 4; ++r)
            o_s[wave * 16 + (lane >> 4) * 4 + r][cf * 16 + (lane & 15)] = acc[cf][r];

    if (ST) {
        // invalid rows contribute exact 0 (A rows zeroed, no bias)
#pragma unroll
        for (int cf = 0; cf < NCF; ++cf) {
            float s = acc[cf][0] + acc[cf][1] + acc[cf][2] + acc[cf][3];
            float q = acc[cf][0] * acc[cf][0] + acc[cf][1] * acc[cf][1]
                    + acc[cf][2] * acc[cf][2] + acc[cf][3] * acc[cf][3];
            s += __shfl_xor(s, 16); s += __shfl_xor(s, 32);
            q += __shfl_xor(q, 16); q += __shfl_xor(q, 32);
            if (lane < 16) {
                sum_s[wave][cf * 16 + lane] = s;
                sq_s[wave][cf * 16 + lane] = q;
            }
        }
    }
    __syncthreads();

    const int r = t >> 2, q = t & 3;
    const int grow = row0 + r;
    if (grow < NND) {
        if (MODE == 0) {
            unsigned short* out = (unsigned short*)outv;
            const int c0 = q * 32;
#pragma unroll
            for (int g = 0; g < 4; ++g) {   // 8 bf16 per uint4
                float v0 = o_s[r][c0 + g * 8 + 0], v1 = o_s[r][c0 + g * 8 + 1];
                float v2 = o_s[r][c0 + g * 8 + 2], v3 = o_s[r][c0 + g * 8 + 3];
                float v4 = o_s[r][c0 + g * 8 + 4], v5 = o_s[r][c0 + g * 8 + 5];
                float v6 = o_s[r][c0 + g * 8 + 6], v7 = o_s[r][c0 + g * 8 + 7];
                uint4 o;
                o.x = f2b(v0) | ((unsigned)f2b(v1) << 16);
                o.y = f2b(v2) | ((unsigned)f2b(v3) << 16);
                o.z = f2b(v4) | ((unsigned)f2b(v5) << 16);
                o.w = f2b(v6) | ((unsigned)f2b(v7) << 16);
                ((uint4*)(out + (size_t)grow * NCOL + c0))[g] = o;
            }
        } else {
            if (q < 2) {
                const int c0 = q * 32;      // cols 0..63 -> tbuf bf16
#pragma unroll
                for (int g = 0; g < 4; ++g) {
                    float v0 = o_s[r][c0 + g * 8 + 0], v1 = o_s[r][c0 + g * 8 + 1];
                    float v2 = o_s[r][c0 + g * 8 + 2], v3 = o_s[r][c0 + g * 8 + 3];
                    float v4 = o_s[r][c0 + g * 8 + 4], v5 = o_s[r][c0 + g * 8 + 5];
                    float v6 = o_s[r][c0 + g * 8 + 6], v7 = o_s[r][c0 + g * 8 + 7];
                    uint4 o;
                    o.x = f2b(v0) | ((unsigned)f2b(v1) << 16);
                    o.y = f2b(v2) | ((unsigned)f2b(v3) << 16);
                    o.z = f2b(v4) | ((unsigned)f2b(v5) << 16);
                    o.w = f2b(v6) | ((unsigned)f2b(v7) << 16);
                    ((uint4*)(tbuf + (size_t)grow * 64 + c0))[g] = o;
                }
            } else {
                float* out = (float*)outv;
                const int c0 = (q - 2) * 32;  // cols 64..127 -> fp32 out + bias
#pragma unroll
                for (int g = 0; g < 8; ++g) {
                    float4 o;
                    o.x = o_s[r][64 + c0 + g * 4 + 0] + bias[c0 + g * 4 + 0];
                    o.y = o_s[r][64 + c0 + g * 4 + 1] + bias[c0 + g * 4 + 1];
                    o.z = o_s[r][64 + c0 + g * 4 + 2] + bias[c0 + g * 4 + 2];
                    o.w = o_s[r][64 + c0 + g * 4 + 3] + bias[c0 + g * 4 + 3];
                    ((float4*)(out + (size_t)grow * 64 + c0))[g] = o;
                }
            }
        }
    }

    if (ST && t < 128) {
        float s = sum_s[0][t] + sum_s[1][t] + sum_s[2][t] + sum_s[3][t];
        float q2 = sq_s[0][t] + sq_s[1][t] + sq_s[2][t] + sq_s[3][t];
        unsafeAtomicAdd(&stats[t], s);
        unsafeAtomicAdd(&stats[128 + t], q2);
    }
}

// ---------------- BN finalize (per-block, from stats) + ReLU in place ----------------
__global__ __launch_bounds__(256) void bn_relu_kernel(unsigned short* __restrict__ h,
                                                      const float* __restrict__ stats,
                                                      const float* __restrict__ gamma,
                                                      const float* __restrict__ beta) {
    __shared__ float ab_s[256];
    int t = threadIdx.x;
    if (t < 128) {
        float mu = stats[t] * (1.0f / NND);
        float var = stats[128 + t] * (1.0f / NND) - mu * mu;
        float rs = rsqrtf(var + EPSBN);
        float a = gamma[t] * rs;
        ab_s[t] = a;
        ab_s[128 + t] = beta[t] - mu * a;
    }
    __syncthreads();
    int i = blockIdx.x * 256 + t;
    if (i >= NND * 16) return;
    uint4 v = ((uint4*)h)[i];
    int c0 = (i & 15) * 8;
    float o[8] = {bf_lo(v.x), bf_hi(v.x), bf_lo(v.y), bf_hi(v.y),
                  bf_lo(v.z), bf_hi(v.z), bf_lo(v.w), bf_hi(v.w)};
#pragma unroll
    for (int j = 0; j < 8; ++j)
        o[j] = fmaxf(o[j] * ab_s[c0 + j] + ab_s[128 + c0 + j], 0.f);
    uint4 w;
    w.x = f2b(o[0]) | ((unsigned)f2b(o[1]) << 16);
    w.y = f2b(o[2]) | ((unsigned)f2b(o[3]) << 16);
    w.z = f2b(o[4]) | ((unsigned)f2b(o[5]) << 16);
    w.w = f2b(o[6]) | ((unsigned)f2b(o[7]) << 16);
    ((uint4*)h)[i] = w;
}

extern "C" void kernel_launch(void* const* d_in, const int* in_sizes, int n_in,
                              void* d_out, int out_size, void* d_ws, size_t ws_size,
                              hipStream_t stream) {
    const float* x   = (const float*)d_in[0];
    const int*   ei  = (const int*)d_in[1];
    const int* src = ei;
    const int* dst = ei + NED;
    const float* Wl0 = (const float*)d_in[2];
    const float* Wr0 = (const float*)d_in[3];
    const float* g0  = (const float*)d_in[5];
    const float* be0 = (const float*)d_in[6];
    const float* Wl1 = (const float*)d_in[7];
    const float* Wr1 = (const float*)d_in[8];
    const float* g1  = (const float*)d_in[10];
    const float* be1 = (const float*)d_in[11];
    const float* Wl2 = (const float*)d_in[12];
    const float* Wr2 = (const float*)d_in[13];
    const float* b2  = (const float*)d_in[14];
    float* out = (float*)d_out;
    // b0/b1 unused: bias cancels under training-mode BatchNorm.

    // workspace (~45.8 MB): aggb | xb (reused as t) | h (bf16 NF each) |
    //   csr int | dinv | rowptr | binOff | cntT[SCPAD] | psum | wpack x3 | stats x2
    // pairs (6.4 MB) aliases aggb (12.8 MB): consumed by bucket_finalize before
    // gather128 #1 writes aggb (stream order).
    const size_t NF = (size_t)NND * 128;
    unsigned short* aggb = (unsigned short*)d_ws;
    unsigned short* xb   = aggb + NF;
    unsigned short* h    = xb + NF;
    int*   csr    = (int*)(h + NF);                // NED ints = 6.4 MB
    float* dinv   = (float*)(csr + NED);
    int*   rowptr = (int*)(dinv + NND);            // NND+1 used, pad to NND+8
    int*   binOff = rowptr + NND + 8;              // NB+1 -> pad 256
    int*   cntT   = binOff + 256;                  // SCPAD = 38912
    int*   psum   = cntT + SCPAD;                  // 38 -> pad 64
    unsigned short* wp0 = (unsigned short*)(psum + 64);
    unsigned short* wp1 = wp0 + 32768;
    unsigned short* wp2 = wp1 + 32768;
    float* stats  = (float*)(wp2 + 32768);         // [0..255]=L0, [256..511]=L1
    unsigned* pairs = (unsigned*)aggb;

    const int GB = (NND + 3) / 4;       // gather blocks (4 nodes each)
    const int GM = (NND + 63) / 64;     // gemm blocks

    // ---- bf16 cast + blocked counting-sort CSR build ----
    cast_bf16_kernel<<<(NND * 16 + 255) / 256, 256, 0, stream>>>(x, xb);
    eb_hist_kernel<<<NB, 256, 0, stream>>>(dst, cntT);
    scan_p1_kernel<<<38, 1024, 0, stream>>>(cntT, psum);
    scan_p2_kernel<<<1, 64, 0, stream>>>(psum, binOff, rowptr);
    scan_p3_kernel<<<38, 1024, 0, stream>>>(cntT, psum, binOff);
    eb_scatter_kernel<<<NB, 256, 0, stream>>>(src, dst, cntT, pairs);
    bucket_finalize_kernel<<<NB, 256, 0, stream>>>(pairs, binOff, rowptr, dinv, csr);
    pack_all_kernel<<<40, 256, 0, stream>>>(Wl0, Wr0, Wl1, Wr1, Wl2, Wr2, wp0, wp1, wp2, stats);

    // ---- layer 0: xb -> h ----
    gather128_kernel<<<GB, 256, 0, stream>>>(xb, rowptr, csr, dinv, aggb);
    gemm_mfma_kernel<8, 0><<<GM, 256, 0, stream>>>(aggb, xb, wp0, nullptr, h, nullptr, stats);
    bn_relu_kernel<<<(NND * 16 + 255) / 256, 256, 0, stream>>>(h, stats, g0, be0);

    // ---- layer 1: h -> h (in-place) ----
    gather128_kernel<<<GB, 256, 0, stream>>>(h, rowptr, csr, dinv, aggb);
    gemm_mfma_kernel<8, 0><<<GM, 256, 0, stream>>>(aggb, h, wp1, nullptr, h, nullptr, stats + 256);
    bn_relu_kernel<<<(NND * 16 + 255) / 256, 256, 0, stream>>>(h, stats + 256, g1, be1);

    // ---- layer 2 (transform-before-aggregate):
    //      t = h@Wl2^T (bf16, into xb), out = h@Wr2^T + b2 (fp32), then out += gather_mean(t)
    gemm_mfma_kernel<4, 2><<<GM, 256, 0, stream>>>(nullptr, h, wp2, b2, out, xb, nullptr);
    gather64_kernel<<<GB, 256, 0, stream>>>(xb, rowptr, csr, dinv, out);
}